// Round 15
// baseline (235.287 us; speedup 1.0000x reference)
//
#include <hip/hip_runtime.h>
#include <hip/hip_bf16.h>
#include <stdint.h>

#define S_LEN  2048
#define DMODEL 2048
#define NHEADS 16
#define DHEAD  128
#define NBATCH 2
#define MROWS  (NBATCH * S_LEN)   // 4096

typedef __bf16 bf16_t;
typedef __bf16 bf16x8 __attribute__((ext_vector_type(8)));
typedef float  f32x4  __attribute__((ext_vector_type(4)));
typedef float  f32x16 __attribute__((ext_vector_type(16)));

#define MFMA_BF16(A, B, C) __builtin_amdgcn_mfma_f32_16x16x32_bf16((A), (B), (C), 0, 0, 0)
#define MFMA32(A, B, C)    __builtin_amdgcn_mfma_f32_32x32x16_bf16((A), (B), (C), 0, 0, 0)

__device__ __forceinline__ void gload_lds16(const void* g, void* l) {
  __builtin_amdgcn_global_load_lds(
      (__attribute__((address_space(1))) uint32_t*)(uintptr_t)g,
      (__attribute__((address_space(3))) uint32_t*)l,
      16, 0, 0);
}

__device__ __forceinline__ unsigned pk2(float lo, float hi) {
  const unsigned short a = __builtin_bit_cast(unsigned short, (bf16_t)lo);
  const unsigned short b = __builtin_bit_cast(unsigned short, (bf16_t)hi);
  return (unsigned)a | ((unsigned)b << 16);
}

// ---------------- prep: x cast (blocks 4096..8191) + 4x W transpose (0..4095)
__global__ __launch_bounds__(256) void prep_kernel(
    const float* __restrict__ X, bf16_t* __restrict__ Xb,
    const float* __restrict__ W0, const float* __restrict__ W1,
    const float* __restrict__ W2, const float* __restrict__ W3,
    bf16_t* __restrict__ T0, bf16_t* __restrict__ T1,
    bf16_t* __restrict__ T2, bf16_t* __restrict__ T3) {
  const int bid = blockIdx.x;
  if (bid >= 4096) {
    const int i = (bid - 4096) * 256 + threadIdx.x;
    const f32x4 a = ((const f32x4*)X)[2 * i];
    const f32x4 b = ((const f32x4*)X)[2 * i + 1];
    bf16x8 o;
#pragma unroll
    for (int j = 0; j < 4; ++j) { o[j] = (bf16_t)a[j]; o[j + 4] = (bf16_t)b[j]; }
    ((bf16x8*)Xb)[i] = o;
    return;
  }
  const int wz  = bid >> 10;
  const int rem = bid & 1023;
  const float* W; bf16_t* T;
  switch (wz) {
    case 0:  W = W0; T = T0; break;
    case 1:  W = W1; T = T1; break;
    case 2:  W = W2; T = T2; break;
    default: W = W3; T = T3; break;
  }
  __shared__ float tile[64][65];
  const int r0 = (rem >> 5) * 64;
  const int c0 = (rem & 31) * 64;
  const int tx = threadIdx.x & 63;
  const int ty = threadIdx.x >> 6;
#pragma unroll
  for (int i = 0; i < 16; ++i) {
    const int r = ty + i * 4;
    tile[r][tx] = W[(size_t)(r0 + r) * DMODEL + c0 + tx];
  }
  __syncthreads();
#pragma unroll
  for (int i = 0; i < 16; ++i) {
    const int r = ty + i * 4;
    T[(size_t)(c0 + r) * DMODEL + r0 + tx] = (bf16_t)tile[tx][r];
  }
}

// =================== QKV GEMM: BM=64 BN=256 BK=64, 2 workgroups/CU ===============
// R13 2-phase schedule; LDS/buffer = A[64][64] 8KB + B[256][64] 32KB = 40KB,
// dbuf 80KB -> exactly 2 blocks/CU (cross-block stall hiding). 8 waves 2m x 4n,
// per-wave 32x64 (acc[2][4]). Stage units: A = 1 load/thr, B-half = 2 loads/thr.
// Counted waits: steady-state vmcnt(1) once/tile (outstanding {t+1.B x4, t+2.A};
// keep youngest 1); vmcnt(0) last two tiles. Swizzle ch^(row&7), 128B rows.
__global__ __launch_bounds__(512, 4) void gemm_qkv(
    const bf16_t* __restrict__ Xb,
    const bf16_t* __restrict__ WqT, const bf16_t* __restrict__ WkT,
    const bf16_t* __restrict__ WvT,
    const float* __restrict__ bq, const float* __restrict__ bk,
    const float* __restrict__ bv,
    bf16_t* __restrict__ Qg, bf16_t* __restrict__ Kg, bf16_t* __restrict__ VTg) {
  __shared__ __align__(16) char lds[2 * 40960];   // 80 KB
  const int tid  = threadIdx.x;
  const int lane = tid & 63;
  const int w    = tid >> 6;
  const int g    = lane >> 4;
  const int l16  = lane & 15;
  const int wm   = w >> 2;       // 0..1 (m half: 32 rows)
  const int wn   = w & 3;        // 0..3 (n quarter: 64 cols)
  const int NT   = DMODEL / 64;  // 32

  // grid 1536 = 8 XCD x 192; within XCD y-fastest (same B panel for 64 ids)
  const int bid = blockIdx.x;
  const int wg  = (bid & 7) * 192 + (bid >> 3);
  const int y   = wg & 63;            // m-block 0..63
  const int xz  = wg >> 6;            // 0..23
  const int x   = xz & 7;             // n-block
  const int z0  = xz >> 3;            // 0=Q 1=K 2=V
  const int m0  = y * 64;
  const int n0  = x * 256;
  const bf16_t* Bt  = (z0 == 0) ? WqT : (z0 == 1) ? WkT : WvT;
  const float* bias = (z0 == 0) ? bq  : (z0 == 1) ? bk  : bv;

  f32x4 acc[2][4];
#pragma unroll
  for (int i = 0; i < 2; ++i)
#pragma unroll
    for (int j = 0; j < 4; ++j) acc[i][j] = (f32x4){0.f, 0.f, 0.f, 0.f};

  auto stageA = [&](int tile) {
    if (tile >= NT) return;
    const int kt  = tile << 6;
    const int row = tid >> 3, ch = tid & 7;
    gload_lds16(Xb + (size_t)(m0 + row) * DMODEL + kt + ((ch ^ (row & 7)) << 3),
                lds + (tile & 1) * 40960 + (tid & ~63) * 16);
  };
  auto stageB = [&](int tile, int h) {
    if (tile >= NT) return;
    const int kt = tile << 6;
    char* db = lds + (tile & 1) * 40960 + 8192 + h * 16384;
    const bf16_t* sb = Bt + (size_t)(n0 + h * 128) * DMODEL + kt;
#pragma unroll
    for (int jj = 0; jj < 2; ++jj) {
      const int c   = jj * 512 + tid;
      const int row = c >> 3, ch = c & 7;
      gload_lds16(sb + (size_t)row * DMODEL + ((ch ^ (row & 7)) << 3),
                  db + (jj * 512 + (tid & ~63)) * 16);
    }
  };

  // prologue: t0 {A,B0,B1} (5 loads) + t1.A (1); wait keeps t1.A in flight
  stageA(0); stageB(0, 0); stageB(0, 1); stageA(1);
  asm volatile("s_waitcnt vmcnt(1)" ::: "memory");
  __builtin_amdgcn_s_barrier();

#pragma unroll 2
  for (int t = 0; t < NT; ++t) {
    const char* cbA = lds + (t & 1) * 40960;
    const char* cbB = cbA + 8192;
    bf16x8 af[2][2], b0[2][2], b1[2][2];
    // ---- phase 0: read A frags (4) + B nj 0-1 (4); stage t+1.B halves
#pragma unroll
    for (int i = 0; i < 2; ++i) {
      const int row = wm * 32 + i * 16 + l16;
      const char* rp = cbA + row * 128;
#pragma unroll
      for (int ks = 0; ks < 2; ++ks)
        af[i][ks] = *(const bf16x8*)(rp + ((((ks << 2) | g) ^ (row & 7)) << 4));
    }
#pragma unroll
    for (int j = 0; j < 2; ++j) {
      const int row = wn * 64 + j * 16 + l16;
      const char* rp = cbB + row * 128;
#pragma unroll
      for (int ks = 0; ks < 2; ++ks)
        b0[j][ks] = *(const bf16x8*)(rp + ((((ks << 2) | g) ^ (row & 7)) << 4));
    }
    stageB(t + 1, 0); stageB(t + 1, 1);
    asm volatile("s_waitcnt lgkmcnt(0)" ::: "memory");
#pragma unroll
    for (int i = 0; i < 2; ++i)
#pragma unroll
      for (int j = 0; j < 2; ++j) {
        acc[i][j] = MFMA_BF16(af[i][0], b0[j][0], acc[i][j]);
        acc[i][j] = MFMA_BF16(af[i][1], b0[j][1], acc[i][j]);
      }
    __builtin_amdgcn_s_barrier();   // B1: all waves' A reads complete
    // ---- phase 1: read B nj 2-3 (4); stage t+2.A (A region now dead)
#pragma unroll
    for (int j = 0; j < 2; ++j) {
      const int row = wn * 64 + (j + 2) * 16 + l16;
      const char* rp = cbB + row * 128;
#pragma unroll
      for (int ks = 0; ks < 2; ++ks)
        b1[j][ks] = *(const bf16x8*)(rp + ((((ks << 2) | g) ^ (row & 7)) << 4));
    }
    stageA(t + 2);
    asm volatile("s_waitcnt lgkmcnt(0)" ::: "memory");
#pragma unroll
    for (int i = 0; i < 2; ++i)
#pragma unroll
      for (int j = 0; j < 2; ++j) {
        acc[i][j + 2] = MFMA_BF16(af[i][0], b1[j][0], acc[i][j + 2]);
        acc[i][j + 2] = MFMA_BF16(af[i][1], b1[j][1], acc[i][j + 2]);
      }
    if (t < NT - 2) asm volatile("s_waitcnt vmcnt(1)" ::: "memory");
    else            asm volatile("s_waitcnt vmcnt(0)" ::: "memory");
    __builtin_amdgcn_s_barrier();   // B2: staged tile visible
  }

  const int b  = m0 >> 11;
  if (z0 == 2) {
    // V: transpose through LDS -> VT[bh][d][s]. tr [256][64] stride 72 elems.
    bf16_t* tr = (bf16_t*)lds;    // 256*72*2 = 36864 <= 81920
#pragma unroll
    for (int i = 0; i < 2; ++i) {
#pragma unroll
      for (int j = 0; j < 4; ++j) {
        const int nl = wn * 64 + j * 16 + l16;
        const int ml = wm * 32 + i * 16 + g * 4;
        const float bb = bias[n0 + nl];
        union { unsigned short u[4]; uint64_t v; } pk;
#pragma unroll
        for (int r = 0; r < 4; ++r)
          pk.u[r] = __builtin_bit_cast(unsigned short, (bf16_t)(acc[i][j][r] + bb));
        *(uint64_t*)&tr[nl * 72 + ml] = pk.v;
      }
    }
    __syncthreads();
    const int s0 = m0 & (S_LEN - 1);
#pragma unroll
    for (int it = 0; it < 4; ++it) {
      const int c   = it * 512 + tid;   // 0..2047
      const int nl  = c >> 3;           // 0..255
      const int ml8 = c & 7;            // 0..7
      const bf16x8 v = *(const bf16x8*)&tr[nl * 72 + ml8 * 8];
      const int n  = n0 + nl;
      const int h  = n >> 7, dd = n & (DHEAD - 1);
      *(bf16x8*)(VTg + ((size_t)(b * NHEADS + h) * DHEAD + dd) * S_LEN + s0 + ml8 * 8) = v;
    }
    return;
  }
  bf16_t* outb = (z0 == 0) ? Qg : Kg;
#pragma unroll
  for (int i = 0; i < 2; ++i) {
#pragma unroll
    for (int j = 0; j < 4; ++j) {
      const int n    = n0 + wn * 64 + j * 16 + l16;
      const float bb = bias[n];
      const int h = n >> 7, d = n & (DHEAD - 1);
#pragma unroll
      for (int r = 0; r < 4; ++r) {
        const int m = m0 + wm * 32 + i * 16 + g * 4 + r;
        const int s = m & (S_LEN - 1);
        outb[((size_t)(b * NHEADS + h) * S_LEN + s) * DHEAD + d] =
            (bf16_t)(acc[i][j][r] + bb);
      }
    }
  }
}

// ------------------------------------------- R13 GEMM body (gemm_out; proven)
__device__ __forceinline__ void gemm8_body(const bf16_t* __restrict__ A,
                                           const bf16_t* __restrict__ Bt,
                                           const float* __restrict__ bias,
                                           float* __restrict__ out,
                                           int m0, int n0) {
  __shared__ __align__(16) char lds8[2 * 49152];   // 96 KB
  const int tid  = threadIdx.x;
  const int lane = tid & 63;
  const int w    = tid >> 6;
  const int g    = lane >> 4;
  const int l16  = lane & 15;
  const int wm   = w >> 2;
  const int wn   = w & 3;

  f32x4 acc[4][4];
#pragma unroll
  for (int i = 0; i < 4; ++i)
#pragma unroll
    for (int j = 0; j < 4; ++j) acc[i][j] = (f32x4){0.f, 0.f, 0.f, 0.f};

  const int st_r0 = tid >> 3;
  const int st_ch = tid & 7;

  auto stage = [&](int tile, int r) {
    if (tile >= DMODEL / 64) return;
    const int kt = tile << 6;
    char* db = lds8 + (tile & 1) * 49152 + r * 16384 + w * 1024;
    const bf16_t* sb = (r == 0) ? (A + (size_t)m0 * DMODEL + kt)
                                : (Bt + (size_t)(n0 + ((r - 1) << 7)) * DMODEL + kt);
#pragma unroll
    for (int jj = 0; jj < 2; ++jj) {
      const int row = jj * 64 + st_r0;
      gload_lds16(sb + (size_t)row * DMODEL + ((st_ch ^ (row & 7)) << 3),
                  db + jj * 8192);
    }
  };

  stage(0, 0); stage(0, 1); stage(0, 2); stage(1, 0);
  asm volatile("s_waitcnt vmcnt(2)" ::: "memory");
  __builtin_amdgcn_s_barrier();

#pragma unroll 2
  for (int t = 0; t < DMODEL / 64; ++t) {
    const char* cb = lds8 + (t & 1) * 49152;
    bf16x8 af[4][2], b0[2][2], b1[2][2];
#pragma unroll
    for (int i = 0; i < 4; ++i) {
      const int row = wm * 64 + i * 16 + l16;
      const char* rp = cb + row * 128;
#pragma unroll
      for (int ks = 0; ks < 2; ++ks)
        af[i][ks] = *(const bf16x8*)(rp + ((((ks << 2) | g) ^ (row & 7)) << 4));
    }
#pragma unroll
    for (int j = 0; j < 2; ++j) {
      const int row = (wn & 1) * 64 + j * 16 + l16;
      const char* rp = cb + 16384 + (wn >> 1) * 16384 + row * 128;
#pragma unroll
      for (int ks = 0; ks < 2; ++ks)
        b0[j][ks] = *(const bf16x8*)(rp + ((((ks << 2) | g) ^ (row & 7)) << 4));
    }
    stage(t + 1, 1); stage(t + 1, 2);
    asm volatile("s_waitcnt lgkmcnt(0)" ::: "memory");
#pragma unroll
    for (int i = 0; i < 4; ++i)
#pragma unroll
      for (int j = 0; j < 2; ++j) {
        acc[i][j] = MFMA_BF16(af[i][0], b0[j][0], acc[i][j]);
        acc[i][j] = MFMA_BF16(af[i][1], b0[j][1], acc[i][j]);
      }
    __builtin_amdgcn_s_barrier();
#pragma unroll
    for (int j = 0; j < 2; ++j) {
      const int row = (wn & 1) * 64 + (j + 2) * 16 + l16;
      const char* rp = cb + 16384 + (wn >> 1) * 16384 + row * 128;
#pragma unroll
      for (int ks = 0; ks < 2; ++ks)
        b1[j][ks] = *(const bf16x8*)(rp + ((((ks << 2) | g) ^ (row & 7)) << 4));
    }
    stage(t + 2, 0);
    asm volatile("s_waitcnt lgkmcnt(0)" ::: "memory");
#pragma unroll
    for (int i = 0; i < 4; ++i)
#pragma unroll
      for (int j = 0; j < 2; ++j) {
        acc[i][j + 2] = MFMA_BF16(af[i][0], b1[j][0], acc[i][j + 2]);
        acc[i][j + 2] = MFMA_BF16(af[i][1], b1[j][1], acc[i][j + 2]);
      }
    if (t < DMODEL / 64 - 2) asm volatile("s_waitcnt vmcnt(2)" ::: "memory");
    else                     asm volatile("s_waitcnt vmcnt(0)" ::: "memory");
    __builtin_amdgcn_s_barrier();
  }

#pragma unroll
  for (int i = 0; i < 4; ++i) {
#pragma unroll
    for (int j = 0; j < 4; ++j) {
      const int n    = n0 + wn * 64 + j * 16 + l16;
      const float bb = bias[n];
#pragma unroll
      for (int r = 0; r < 4; ++r) {
        const int m = m0 + wm * 64 + i * 16 + g * 4 + r;
        out[(size_t)m * DMODEL + n] = acc[i][j][r] + bb;
      }
    }
  }
}

__global__ __launch_bounds__(512, 2) void gemm_out(
    const bf16_t* __restrict__ Ctx, const bf16_t* __restrict__ WoT,
    const float* __restrict__ bo, float* __restrict__ out) {
  gemm8_body(Ctx, WoT, bo, out, blockIdx.y * 128, blockIdx.x * 256);
}

// --------------------------------------------------------------- flash attention
#define KTILE_B 16384
#define VTILE_B 16384
#define ABUF_B  (KTILE_B + VTILE_B)   // 32 KB per buffer

__global__ __launch_bounds__(256, 2) void attn_kernel(
    const bf16_t* __restrict__ Qg, const bf16_t* __restrict__ Kg,
    const bf16_t* __restrict__ VTg, bf16_t* __restrict__ ctx) {
  __shared__ __align__(16) char ldsbuf[2][ABUF_B];
  __shared__ float lbuf[4][32];

  const int tid  = threadIdx.x;
  const int lane = tid & 63;
  const int w    = tid >> 6;
  const int l31  = lane & 31;
  const int hi   = lane >> 5;

  const int id   = blockIdx.x;                  // 512 blocks
  const int bh   = id & 31;
  const int jraw = id >> 5;
  const int j    = (jraw < 8) ? jraw : 23 - jraw;
  const int q0   = j * 128;
  const int qw   = q0 + w * 32;
  const int tq   = (qw + 31) >> 6;
  const int NT   = (q0 + 128) >> 6;

  const size_t bho = (size_t)bh * S_LEN * DHEAD;
  const bf16_t* Qb  = Qg + bho;
  const bf16_t* Kb  = Kg + bho;
  const bf16_t* VTb = VTg + bho;                // [128][2048]

  auto stageT = [&](int t) {
    const int kt = t << 6;
    char* dst = ldsbuf[t & 1];
#pragma unroll
    for (int i = 0; i < 4; ++i) {                 // K: 64 rows x 256B
      const int c   = i * 256 + tid;
      const int row = c >> 4, ch = c & 15;
      gload_lds16(Kb + (size_t)(kt + row) * DHEAD + ((ch ^ (row & 7)) << 3),
                  dst + (i * 256 + (tid & ~63)) * 16);
    }
#pragma unroll
    for (int i = 0; i < 4; ++i) {                 // VT: 128 rows x 128B
      const int c   = i * 256 + tid;
      const int row = c >> 3, ch = c & 7;
      gload_lds16(VTb + (size_t)row * S_LEN + kt + ((ch ^ (row & 7)) << 3),
                  dst + KTILE_B + (i * 256 + (tid & ~63)) * 16);
    }
  };

  bf16x8 qreg[8];
#pragma unroll
  for (int s = 0; s < 8; ++s)
    qreg[s] = *(const bf16x8*)(Qb + (size_t)(qw + l31) * DHEAD + s * 16 + hi * 8);

  f32x16 oacc[4];
#pragma unroll
  for (int d0 = 0; d0 < 4; ++d0)
#pragma unroll
    for (int e = 0; e < 16; ++e) oacc[d0][e] = 0.f;

  float m = -1e30f, lsum = 0.f;
  const float sc2 = 0.12751751135f;             // log2(e)/sqrt(128)

  stageT(0);
  asm volatile("s_waitcnt vmcnt(0)" ::: "memory");
  __syncthreads();

  for (int t = 0; t < NT; ++t) {
    const char* bK = ldsbuf[t & 1];
    const char* bV = bK + KTILE_B;
    if (t + 1 < NT) stageT(t + 1);

    if (t <= tq) {
      const int kt = t << 6;
      f32x16 stt[2];
#pragma unroll
      for (int kh = 0; kh < 2; ++kh)
#pragma unroll
        for (int e = 0; e < 16; ++e) stt[kh][e] = 0.f;
      __builtin_amdgcn_s_setprio(1);
#pragma unroll
      for (int kh = 0; kh < 2; ++kh) {
        const int row = kh * 32 + l31;
        const char* rb = bK + row * 256;
        const int swz = (row & 7) << 4;
#pragma unroll
        for (int s = 0; s < 8; ++s) {
          const bf16x8 kf = *(const bf16x8*)(rb + ((((s << 1) | hi) << 4) ^ swz));
          stt[kh] = MFMA32(kf, qreg[s], stt[kh]);
        }
      }
      __builtin_amdgcn_s_setprio(0);
      if (t == tq) {
        const int qg = qw + l31;
#pragma unroll
        for (int kh = 0; kh < 2; ++kh)
#pragma unroll
          for (int r = 0; r < 16; ++r) {
            const int kv = kt + kh * 32 + (r & 3) + 8 * (r >> 2) + 4 * hi;
            stt[kh][r] = (kv > qg) ? -1e30f : stt[kh][r];
          }
      }
      float pm = fmaxf(stt[0][0], stt[1][0]);
#pragma unroll
      for (int r = 1; r < 16; ++r)
        pm = fmaxf(pm, fmaxf(stt[0][r], stt[1][r]));
      pm = fmaxf(pm, __shfl_xor(pm, 32));
      const float pmax = pm * sc2;
      if (!__all(pmax <= m + 8.f)) {
        const float mn   = fmaxf(m, pmax);
        const float corr = __builtin_amdgcn_exp2f(m - mn);
        m = mn;
        lsum *= corr;
        if (!hi) lbuf[w][l31] = corr;
#pragma unroll
        for (int r = 0; r < 16; ++r) {
          const float cr = lbuf[w][(r & 3) + 8 * (r >> 2) + 4 * hi];
#pragma unroll
          for (int d0 = 0; d0 < 4; ++d0) oacc[d0][r] *= cr;
        }
      }
      float rs = 0.f;
#pragma unroll
      for (int kh = 0; kh < 2; ++kh)
#pragma unroll
        for (int r = 0; r < 16; ++r) {
          const float p = __builtin_amdgcn_exp2f(__builtin_fmaf(stt[kh][r], sc2, -m));
          stt[kh][r] = p;
          rs += p;
        }
      rs += __shfl_xor(rs, 32);
      lsum += rs;
      unsigned pw_[2][8];
#pragma unroll
      for (int kh = 0; kh < 2; ++kh)
#pragma unroll
        for (int jj = 0; jj < 8; ++jj)
          pw_[kh][jj] = pk2(stt[kh][2 * jj], stt[kh][2 * jj + 1]);
      bf16x8 pa[4];
#pragma unroll
      for (int kh = 0; kh < 2; ++kh)
#pragma unroll
        for (int c2 = 0; c2 < 2; ++c2) {
          const unsigned o0 = pw_[kh][4 * c2 + 0], o1 = pw_[kh][4 * c2 + 1];
          const unsigned o2 = pw_[kh][4 * c2 + 2], o3 = pw_[kh][4 * c2 + 3];
          const unsigned p0 = (unsigned)__shfl_xor((int)o0, 32);
          const unsigned p1 = (unsigned)__shfl_xor((int)o1, 32);
          const unsigned p2 = (unsigned)__shfl_xor((int)o2, 32);
          const unsigned p3 = (unsigned)__shfl_xor((int)o3, 32);
          union { unsigned u[4]; bf16x8 v; } uu;
          uu.u[0] = hi ? p2 : o0;
          uu.u[1] = hi ? p3 : o1;
          uu.u[2] = hi ? o2 : p0;
          uu.u[3] = hi ? o3 : p1;
          pa[2 * kh + c2] = uu.v;
        }
      __builtin_amdgcn_s_setprio(1);
#pragma unroll
      for (int d0 = 0; d0 < 4; ++d0) {
        const int row = d0 * 32 + l31;
        const char* rb = bV + row * 128;
        const int swz = (row & 7) << 4;
#pragma unroll
        for (int ks = 0; ks < 4; ++ks) {
          const bf16x8 vb = *(const bf16x8*)(rb + ((((ks << 1) | hi) << 4) ^ swz));
          oacc[d0] = MFMA32(pa[ks], vb, oacc[d0]);
        }
      }
      __builtin_amdgcn_s_setprio(0);
    }
    asm volatile("s_waitcnt vmcnt(0)" ::: "memory");
    __syncthreads();
  }

  if (!hi) lbuf[w][l31] = 1.0f / lsum;
  const int b = bh >> 4, h = bh & 15;
#pragma unroll
  for (int r = 0; r < 16; ++r) {
    const int cro = (r & 3) + 8 * (r >> 2) + 4 * hi;
    const float li = lbuf[w][cro];
    const size_t base = ((size_t)(b * S_LEN + qw + cro)) * DMODEL + h * DHEAD;
#pragma unroll
    for (int d0 = 0; d0 < 4; ++d0)
      ctx[base + d0 * 32 + l31] = (bf16_t)(oacc[d0][r] * li);
  }
}

// ------------------------------------------------------------------------- launch
extern "C" void kernel_launch(void* const* d_in, const int* in_sizes, int n_in,
                              void* d_out, int out_size, void* d_ws, size_t ws_size,
                              hipStream_t stream) {
  const float* x  = (const float*)d_in[0];
  const float* Wq = (const float*)d_in[1];
  const float* bq = (const float*)d_in[2];
  const float* Wk = (const float*)d_in[3];
  const float* bk = (const float*)d_in[4];
  const float* Wv = (const float*)d_in[5];
  const float* bv = (const float*)d_in[6];
  const float* Wo = (const float*)d_in[7];
  const float* bo = (const float*)d_in[8];

  char* ws = (char*)d_ws;
  const size_t MB = 1ull << 20;
  bf16_t* Xb  = (bf16_t*)(ws + 0);
  bf16_t* WqT = (bf16_t*)(ws + 16 * MB);
  bf16_t* WkT = (bf16_t*)(ws + 24 * MB);
  bf16_t* WvT = (bf16_t*)(ws + 32 * MB);
  bf16_t* WoT = (bf16_t*)(ws + 40 * MB);
  bf16_t* Qg  = (bf16_t*)(ws + 48 * MB);
  bf16_t* Kg  = (bf16_t*)(ws + 64 * MB);
  bf16_t* VTg = (bf16_t*)(ws + 80 * MB);   // V^T written directly by gemm_qkv
  bf16_t* Ctx = (bf16_t*)(ws + 96 * MB);
  if (ws_size < 112 * MB) return;

  prep_kernel<<<dim3(8192), 256, 0, stream>>>(x, Xb, Wq, Wk, Wv, Wo,
                                              WqT, WkT, WvT, WoT);
  gemm_qkv<<<dim3(1536), 512, 0, stream>>>(
      Xb, WqT, WkT, WvT, bq, bk, bv, Qg, Kg, VTg);
  attn_kernel<<<dim3(512), 256, 0, stream>>>(Qg, Kg, VTg, Ctx);
  gemm_out<<<dim3(DMODEL / 256, MROWS / 128), 512, 0, stream>>>(Ctx, WoT, bo, (float*)d_out);
}

// Round 16
// 213.258 us; speedup vs baseline: 1.1033x; 1.1033x over previous
//
#include <hip/hip_runtime.h>
#include <hip/hip_bf16.h>
#include <stdint.h>

#define S_LEN  2048
#define DMODEL 2048
#define NHEADS 16
#define DHEAD  128
#define NBATCH 2
#define MROWS  (NBATCH * S_LEN)   // 4096

typedef __bf16 bf16_t;
typedef __bf16 bf16x8 __attribute__((ext_vector_type(8)));
typedef float  f32x4  __attribute__((ext_vector_type(4)));
typedef float  f32x16 __attribute__((ext_vector_type(16)));

#define MFMA_BF16(A, B, C) __builtin_amdgcn_mfma_f32_16x16x32_bf16((A), (B), (C), 0, 0, 0)
#define MFMA32(A, B, C)    __builtin_amdgcn_mfma_f32_32x32x16_bf16((A), (B), (C), 0, 0, 0)

__device__ __forceinline__ void gload_lds16(const void* g, void* l) {
  __builtin_amdgcn_global_load_lds(
      (__attribute__((address_space(1))) uint32_t*)(uintptr_t)g,
      (__attribute__((address_space(3))) uint32_t*)l,
      16, 0, 0);
}

__device__ __forceinline__ unsigned pk2(float lo, float hi) {
  const unsigned short a = __builtin_bit_cast(unsigned short, (bf16_t)lo);
  const unsigned short b = __builtin_bit_cast(unsigned short, (bf16_t)hi);
  return (unsigned)a | ((unsigned)b << 16);
}

// ---------------- prep: x cast (blocks 4096..8191) + 4x W transpose (0..4095)
__global__ __launch_bounds__(256) void prep_kernel(
    const float* __restrict__ X, bf16_t* __restrict__ Xb,
    const float* __restrict__ W0, const float* __restrict__ W1,
    const float* __restrict__ W2, const float* __restrict__ W3,
    bf16_t* __restrict__ T0, bf16_t* __restrict__ T1,
    bf16_t* __restrict__ T2, bf16_t* __restrict__ T3) {
  const int bid = blockIdx.x;
  if (bid >= 4096) {
    const int i = (bid - 4096) * 256 + threadIdx.x;
    const f32x4 a = ((const f32x4*)X)[2 * i];
    const f32x4 b = ((const f32x4*)X)[2 * i + 1];
    bf16x8 o;
#pragma unroll
    for (int j = 0; j < 4; ++j) { o[j] = (bf16_t)a[j]; o[j + 4] = (bf16_t)b[j]; }
    ((bf16x8*)Xb)[i] = o;
    return;
  }
  const int wz  = bid >> 10;
  const int rem = bid & 1023;
  const float* W; bf16_t* T;
  switch (wz) {
    case 0:  W = W0; T = T0; break;
    case 1:  W = W1; T = T1; break;
    case 2:  W = W2; T = T2; break;
    default: W = W3; T = T3; break;
  }
  __shared__ float tile[64][65];
  const int r0 = (rem >> 5) * 64;
  const int c0 = (rem & 31) * 64;
  const int tx = threadIdx.x & 63;
  const int ty = threadIdx.x >> 6;
#pragma unroll
  for (int i = 0; i < 16; ++i) {
    const int r = ty + i * 4;
    tile[r][tx] = W[(size_t)(r0 + r) * DMODEL + c0 + tx];
  }
  __syncthreads();
#pragma unroll
  for (int i = 0; i < 16; ++i) {
    const int r = ty + i * 4;
    T[(size_t)(c0 + r) * DMODEL + r0 + tx] = (bf16_t)tile[tx][r];
  }
}

// ------------------------------------------- R13 GEMM body: BM=128 BN=256 BK=64
// 2 barriers/K-tile (B1 fences stage(t+2,A) overwrite; B2 post-vmcnt visibility).
// Explicit lgkmcnt(0) drains kept (R14 showed removal is neutral-to-negative).
// Epilogue: mode 0 bf16 scatter [B,H,S,D]; mode 1 f32 [M][2048]; mode 2 VT.
__device__ __forceinline__ void gemm8_body(const bf16_t* __restrict__ A,
                                           const bf16_t* __restrict__ Bt,
                                           const float* __restrict__ bias,
                                           void* __restrict__ out,
                                           int m0, int n0, int mode) {
  __shared__ __align__(16) char lds8[2 * 49152];   // 96 KB
  const int tid  = threadIdx.x;
  const int lane = tid & 63;
  const int w    = tid >> 6;
  const int g    = lane >> 4;
  const int l16  = lane & 15;
  const int wm   = w >> 2;       // 0..1
  const int wn   = w & 3;        // 0..3

  f32x4 acc[4][4];
#pragma unroll
  for (int i = 0; i < 4; ++i)
#pragma unroll
    for (int j = 0; j < 4; ++j) acc[i][j] = (f32x4){0.f, 0.f, 0.f, 0.f};

  const int st_r0 = tid >> 3;
  const int st_ch = tid & 7;

  auto stage = [&](int tile, int r) {
    if (tile >= DMODEL / 64) return;
    const int kt = tile << 6;
    char* db = lds8 + (tile & 1) * 49152 + r * 16384 + w * 1024;
    const bf16_t* sb = (r == 0) ? (A + (size_t)m0 * DMODEL + kt)
                                : (Bt + (size_t)(n0 + ((r - 1) << 7)) * DMODEL + kt);
#pragma unroll
    for (int jj = 0; jj < 2; ++jj) {
      const int row = jj * 64 + st_r0;
      gload_lds16(sb + (size_t)row * DMODEL + ((st_ch ^ (row & 7)) << 3),
                  db + jj * 8192);
    }
  };

  stage(0, 0); stage(0, 1); stage(0, 2); stage(1, 0);
  asm volatile("s_waitcnt vmcnt(2)" ::: "memory");
  __builtin_amdgcn_s_barrier();

#pragma unroll 2
  for (int t = 0; t < DMODEL / 64; ++t) {
    const char* cb = lds8 + (t & 1) * 49152;
    bf16x8 af[4][2], b0[2][2], b1[2][2];
    // ---- phase 0: read A frags + B(nj 0-1); stage t+1 B halves; MFMA
#pragma unroll
    for (int i = 0; i < 4; ++i) {
      const int row = wm * 64 + i * 16 + l16;
      const char* rp = cb + row * 128;
#pragma unroll
      for (int ks = 0; ks < 2; ++ks)
        af[i][ks] = *(const bf16x8*)(rp + ((((ks << 2) | g) ^ (row & 7)) << 4));
    }
#pragma unroll
    for (int j = 0; j < 2; ++j) {
      const int row = (wn & 1) * 64 + j * 16 + l16;
      const char* rp = cb + 16384 + (wn >> 1) * 16384 + row * 128;
#pragma unroll
      for (int ks = 0; ks < 2; ++ks)
        b0[j][ks] = *(const bf16x8*)(rp + ((((ks << 2) | g) ^ (row & 7)) << 4));
    }
    stage(t + 1, 1); stage(t + 1, 2);
    asm volatile("s_waitcnt lgkmcnt(0)" ::: "memory");
#pragma unroll
    for (int i = 0; i < 4; ++i)
#pragma unroll
      for (int j = 0; j < 2; ++j) {
        acc[i][j] = MFMA_BF16(af[i][0], b0[j][0], acc[i][j]);
        acc[i][j] = MFMA_BF16(af[i][1], b0[j][1], acc[i][j]);
      }
    __builtin_amdgcn_s_barrier();   // B1: all waves' phase-0 reads complete
    // ---- phase 1: read B(nj 2-3); stage t+2 A (A-region now dead); MFMA
#pragma unroll
    for (int j = 0; j < 2; ++j) {
      const int row = (wn & 1) * 64 + (j + 2) * 16 + l16;
      const char* rp = cb + 16384 + (wn >> 1) * 16384 + row * 128;
#pragma unroll
      for (int ks = 0; ks < 2; ++ks)
        b1[j][ks] = *(const bf16x8*)(rp + ((((ks << 2) | g) ^ (row & 7)) << 4));
    }
    stage(t + 2, 0);
    asm volatile("s_waitcnt lgkmcnt(0)" ::: "memory");
#pragma unroll
    for (int i = 0; i < 4; ++i)
#pragma unroll
      for (int j = 0; j < 2; ++j) {
        acc[i][j + 2] = MFMA_BF16(af[i][0], b1[j][0], acc[i][j + 2]);
        acc[i][j + 2] = MFMA_BF16(af[i][1], b1[j][1], acc[i][j + 2]);
      }
    if (t < DMODEL / 64 - 2) asm volatile("s_waitcnt vmcnt(2)" ::: "memory");
    else                     asm volatile("s_waitcnt vmcnt(0)" ::: "memory");
    __builtin_amdgcn_s_barrier();   // B2: staged tile visible to all waves
  }

  if (mode == 2) {
    // V: transpose through LDS, write VT[bh][d][s] coalesced.
    bf16_t* tr = (bf16_t*)lds8;      // [n 256][m 128] stride 136 elems
#pragma unroll
    for (int i = 0; i < 4; ++i) {
#pragma unroll
      for (int j = 0; j < 4; ++j) {
        const int nl = wn * 64 + j * 16 + l16;
        const int ml = wm * 64 + i * 16 + g * 4;
        const float bb = bias[n0 + nl];
        union { unsigned short u[4]; uint64_t v; } pk;
#pragma unroll
        for (int r = 0; r < 4; ++r)
          pk.u[r] = __builtin_bit_cast(unsigned short, (bf16_t)(acc[i][j][r] + bb));
        *(uint64_t*)&tr[nl * 136 + ml] = pk.v;
      }
    }
    __syncthreads();
    const int b = m0 >> 11;
    const int s0 = m0 & (S_LEN - 1);
#pragma unroll
    for (int it = 0; it < 8; ++it) {
      const int c   = it * 512 + tid;   // 0..4095 exactly
      const int nl  = c >> 4;
      const int ml8 = c & 15;
      const bf16x8 v = *(const bf16x8*)&tr[nl * 136 + ml8 * 8];
      const int n  = n0 + nl;
      const int h  = n >> 7, dd = n & (DHEAD - 1);
      *(bf16x8*)((bf16_t*)out +
                 ((size_t)(b * NHEADS + h) * DHEAD + dd) * S_LEN + s0 + ml8 * 8) = v;
    }
    return;
  }

#pragma unroll
  for (int i = 0; i < 4; ++i) {
#pragma unroll
    for (int j = 0; j < 4; ++j) {
      const int n    = n0 + wn * 64 + j * 16 + l16;
      const float bb = bias[n];
#pragma unroll
      for (int r = 0; r < 4; ++r) {
        const int m   = m0 + wm * 64 + i * 16 + g * 4 + r;
        const float v = acc[i][j][r] + bb;
        if (mode == 0) {
          const int b = m >> 11, s = m & (S_LEN - 1);
          const int h = n >> 7,  d = n & (DHEAD - 1);
          ((bf16_t*)out)[((size_t)(b * NHEADS + h) * S_LEN + s) * DHEAD + d] = (bf16_t)v;
        } else {
          ((float*)out)[(size_t)m * DMODEL + n] = v;
        }
      }
    }
  }
}

// QKV: 1-D grid 768, bijective XCD swizzle (768 = 8 XCD x 96).
__global__ __launch_bounds__(512, 2) void gemm_qkv(
    const bf16_t* __restrict__ Xb,
    const bf16_t* __restrict__ WqT, const bf16_t* __restrict__ WkT,
    const bf16_t* __restrict__ WvT,
    const float* __restrict__ bq, const float* __restrict__ bk,
    const float* __restrict__ bv,
    bf16_t* __restrict__ Qg, bf16_t* __restrict__ Kg, bf16_t* __restrict__ VTg) {
  const int bid = blockIdx.x;
  const int wg  = (bid & 7) * 96 + (bid >> 3);
  const int x   = wg & 7;
  const int y   = (wg >> 3) & 31;
  const int z0  = wg >> 8;
  const bf16_t* Bt  = (z0 == 0) ? WqT : (z0 == 1) ? WkT : WvT;
  const float* bias = (z0 == 0) ? bq  : (z0 == 1) ? bk  : bv;
  void* out         = (z0 == 0) ? (void*)Qg : (z0 == 1) ? (void*)Kg : (void*)VTg;
  gemm8_body(Xb, Bt, bias, out, y * 128, x * 256, (z0 == 2) ? 2 : 0);
}

// out-proj: grid 256 = 8 XCD x 32, bijective swizzle (4 A-panels x 8 B per XCD)
__global__ __launch_bounds__(512, 2) void gemm_out(
    const bf16_t* __restrict__ Ctx, const bf16_t* __restrict__ WoT,
    const float* __restrict__ bo, float* __restrict__ out) {
  const int bid = blockIdx.x;
  const int wg  = (bid & 7) * 32 + (bid >> 3);
  const int x   = wg & 7;
  const int y   = wg >> 3;
  gemm8_body(Ctx, WoT, bo, out, y * 128, x * 256, 1);
}

// --------------------------------------------------------------- flash attention
#define KTILE_B 16384
#define VTILE_B 16384
#define ABUF_B  (KTILE_B + VTILE_B)   // 32 KB per buffer

__global__ __launch_bounds__(256, 2) void attn_kernel(
    const bf16_t* __restrict__ Qg, const bf16_t* __restrict__ Kg,
    const bf16_t* __restrict__ VTg, bf16_t* __restrict__ ctx) {
  __shared__ __align__(16) char ldsbuf[2][ABUF_B];
  __shared__ float lbuf[4][32];

  const int tid  = threadIdx.x;
  const int lane = tid & 63;
  const int w    = tid >> 6;
  const int l31  = lane & 31;
  const int hi   = lane >> 5;

  const int id   = blockIdx.x;                  // 512 blocks
  const int bh   = id & 31;
  const int jraw = id >> 5;
  const int j    = (jraw < 8) ? jraw : 23 - jraw;
  const int q0   = j * 128;
  const int qw   = q0 + w * 32;
  const int tq   = (qw + 31) >> 6;
  const int NT   = (q0 + 128) >> 6;

  const size_t bho = (size_t)bh * S_LEN * DHEAD;
  const bf16_t* Qb  = Qg + bho;
  const bf16_t* Kb  = Kg + bho;
  const bf16_t* VTb = VTg + bho;                // [128][2048]

  auto stageT = [&](int t) {
    const int kt = t << 6;
    char* dst = ldsbuf[t & 1];
#pragma unroll
    for (int i = 0; i < 4; ++i) {                 // K: 64 rows x 256B
      const int c   = i * 256 + tid;
      const int row = c >> 4, ch = c & 15;
      gload_lds16(Kb + (size_t)(kt + row) * DHEAD + ((ch ^ (row & 7)) << 3),
                  dst + (i * 256 + (tid & ~63)) * 16);
    }
#pragma unroll
    for (int i = 0; i < 4; ++i) {                 // VT: 128 rows x 128B
      const int c   = i * 256 + tid;
      const int row = c >> 3, ch = c & 7;
      gload_lds16(VTb + (size_t)row * S_LEN + kt + ((ch ^ (row & 7)) << 3),
                  dst + KTILE_B + (i * 256 + (tid & ~63)) * 16);
    }
  };

  bf16x8 qreg[8];
#pragma unroll
  for (int s = 0; s < 8; ++s)
    qreg[s] = *(const bf16x8*)(Qb + (size_t)(qw + l31) * DHEAD + s * 16 + hi * 8);

  f32x16 oacc[4];
#pragma unroll
  for (int d0 = 0; d0 < 4; ++d0)
#pragma unroll
    for (int e = 0; e < 16; ++e) oacc[d0][e] = 0.f;

  float m = -1e30f, lsum = 0.f;
  const float sc2 = 0.12751751135f;             // log2(e)/sqrt(128)

  stageT(0);
  asm volatile("s_waitcnt vmcnt(0)" ::: "memory");
  __syncthreads();

  for (int t = 0; t < NT; ++t) {
    const char* bK = ldsbuf[t & 1];
    const char* bV = bK + KTILE_B;
    if (t + 1 < NT) stageT(t + 1);

    if (t <= tq) {
      const int kt = t << 6;
      f32x16 stt[2];
#pragma unroll
      for (int kh = 0; kh < 2; ++kh)
#pragma unroll
        for (int e = 0; e < 16; ++e) stt[kh][e] = 0.f;
#pragma unroll
      for (int kh = 0; kh < 2; ++kh) {
        const int row = kh * 32 + l31;
        const char* rb = bK + row * 256;
        const int swz = (row & 7) << 4;
#pragma unroll
        for (int s = 0; s < 8; ++s) {
          const bf16x8 kf = *(const bf16x8*)(rb + ((((s << 1) | hi) << 4) ^ swz));
          stt[kh] = MFMA32(kf, qreg[s], stt[kh]);
        }
      }
      if (t == tq) {
        const int qg = qw + l31;
#pragma unroll
        for (int kh = 0; kh < 2; ++kh)
#pragma unroll
          for (int r = 0; r < 16; ++r) {
            const int kv = kt + kh * 32 + (r & 3) + 8 * (r >> 2) + 4 * hi;
            stt[kh][r] = (kv > qg) ? -1e30f : stt[kh][r];
          }
      }
      float pm = fmaxf(stt[0][0], stt[1][0]);
#pragma unroll
      for (int r = 1; r < 16; ++r)
        pm = fmaxf(pm, fmaxf(stt[0][r], stt[1][r]));
      pm = fmaxf(pm, __shfl_xor(pm, 32));
      const float pmax = pm * sc2;
      if (!__all(pmax <= m + 8.f)) {
        const float mn   = fmaxf(m, pmax);
        const float corr = __builtin_amdgcn_exp2f(m - mn);
        m = mn;
        lsum *= corr;
        if (!hi) lbuf[w][l31] = corr;
#pragma unroll
        for (int r = 0; r < 16; ++r) {
          const float cr = lbuf[w][(r & 3) + 8 * (r >> 2) + 4 * hi];
#pragma unroll
          for (int d0 = 0; d0 < 4; ++d0) oacc[d0][r] *= cr;
        }
      }
      float rs = 0.f;
#pragma unroll
      for (int kh = 0; kh < 2; ++kh)
#pragma unroll
        for (int r = 0; r < 16; ++r) {
          const float p = __builtin_amdgcn_exp2f(__builtin_fmaf(stt[kh][r], sc2, -m));
          stt[kh][r] = p;
          rs += p;
        }
      rs += __shfl_xor(rs, 32);
      lsum += rs;
      unsigned pw_[2][8];
#pragma unroll
      for (int kh = 0; kh < 2; ++kh)
#pragma unroll
        for (int jj = 0; jj < 8; ++jj)
          pw_[kh][jj] = pk2(stt[kh][2 * jj], stt[kh][2 * jj + 1]);
      bf16x8 pa[4];
#pragma unroll
      for (int kh = 0; kh < 2; ++kh)
#pragma unroll
        for (int c2 = 0; c2 < 2; ++c2) {
          const unsigned o0 = pw_[kh][4 * c2 + 0], o1 = pw_[kh][4 * c2 + 1];
          const unsigned o2 = pw_[kh][4 * c2 + 2], o3 = pw_[kh][4 * c2 + 3];
          const unsigned p0 = (unsigned)__shfl_xor((int)o0, 32);
          const unsigned p1 = (unsigned)__shfl_xor((int)o1, 32);
          const unsigned p2 = (unsigned)__shfl_xor((int)o2, 32);
          const unsigned p3 = (unsigned)__shfl_xor((int)o3, 32);
          union { unsigned u[4]; bf16x8 v; } uu;
          uu.u[0] = hi ? p2 : o0;
          uu.u[1] = hi ? p3 : o1;
          uu.u[2] = hi ? o2 : p0;
          uu.u[3] = hi ? o3 : p1;
          pa[2 * kh + c2] = uu.v;
        }
#pragma unroll
      for (int d0 = 0; d0 < 4; ++d0) {
        const int row = d0 * 32 + l31;
        const char* rb = bV + row * 128;
        const int swz = (row & 7) << 4;
#pragma unroll
        for (int ks = 0; ks < 4; ++ks) {
          const bf16x8 vb = *(const bf16x8*)(rb + ((((ks << 1) | hi) << 4) ^ swz));
          oacc[d0] = MFMA32(pa[ks], vb, oacc[d0]);
        }
      }
    }
    asm volatile("s_waitcnt vmcnt(0)" ::: "memory");
    __syncthreads();
  }

  if (!hi) lbuf[w][l31] = 1.0f / lsum;
  const int b = bh >> 4, h = bh & 15;
#pragma unroll
  for (int r = 0; r < 16; ++r) {
    const int cro = (r & 3) + 8 * (r >> 2) + 4 * hi;
    const float li = lbuf[w][cro];
    const size_t base = ((size_t)(b * S_LEN + qw + cro)) * DMODEL + h * DHEAD;
#pragma unroll
    for (int d0 = 0; d0 < 4; ++d0)
      ctx[base + d0 * 32 + l31] = (bf16_t)(oacc[d0][r] * li);
  }
}

// ------------------------------------------------------------------------- launch
extern "C" void kernel_launch(void* const* d_in, const int* in_sizes, int n_in,
                              void* d_out, int out_size, void* d_ws, size_t ws_size,
                              hipStream_t stream) {
  const float* x  = (const float*)d_in[0];
  const float* Wq = (const float*)d_in[1];
  const float* bq = (const float*)d_in[2];
  const float* Wk = (const float*)d_in[3];
  const float* bk = (const float*)d_in[4];
  const float* Wv = (const float*)d_in[5];
  const float* bv = (const float*)d_in[6];
  const float* Wo = (const float*)d_in[7];
  const float* bo = (const float*)d_in[8];

  char* ws = (char*)d_ws;
  const size_t MB = 1ull << 20;
  bf16_t* Xb  = (bf16_t*)(ws + 0);
  bf16_t* WqT = (bf16_t*)(ws + 16 * MB);
  bf16_t* WkT = (bf16_t*)(ws + 24 * MB);
  bf16_t* WvT = (bf16_t*)(ws + 32 * MB);
  bf16_t* WoT = (bf16_t*)(ws + 40 * MB);
  bf16_t* Qg  = (bf16_t*)(ws + 48 * MB);
  bf16_t* Kg  = (bf16_t*)(ws + 64 * MB);
  bf16_t* VTg = (bf16_t*)(ws + 80 * MB);   // V^T written directly by gemm_qkv
  bf16_t* Ctx = (bf16_t*)(ws + 96 * MB);
  if (ws_size < 112 * MB) return;

  prep_kernel<<<dim3(8192), 256, 0, stream>>>(x, Xb, Wq, Wk, Wv, Wo,
                                              WqT, WkT, WvT, WoT);
  gemm_qkv<<<dim3(768), 512, 0, stream>>>(
      Xb, WqT, WkT, WvT, bq, bk, bv, Qg, Kg, VTg);
  attn_kernel<<<dim3(512), 256, 0, stream>>>(Qg, Kg, VTg, Ctx);
  gemm_out<<<dim3(256), 512, 0, stream>>>(Ctx, WoT, bo, (float*)d_out);
}